// Round 2
// baseline (6361.181 us; speedup 1.0000x reference)
//
#include <hip/hip_runtime.h>

#define DIN 64
#define DH  128
#define SEGS 250000

// ---------------------------------------------------------------------------
// k_bounds: row_start[s] = first row r with index[r] >= s, for s in [0, SEGS].
// index is sorted ascending, values in [0, SEGS). Each thread r covers the
// half-open segment range (index[r-1], index[r]]; thread N-1 also covers the
// tail. Every entry written exactly once -> no races, no init needed.
// ---------------------------------------------------------------------------
__global__ void k_bounds(const int* __restrict__ idx,
                         int* __restrict__ row_start, int N) {
  int r = blockIdx.x * blockDim.x + threadIdx.x;
  if (r >= N) return;
  int cur  = min(max(idx[r], 0), SEGS - 1);               // defensive clamp
  int prev = (r == 0) ? -1 : min(max(idx[r - 1], 0), SEGS - 1);
  for (int s = prev + 1; s <= cur; ++s) row_start[s] = r;
  if (r == N - 1) {
    for (int s = cur + 1; s <= SEGS; ++s) row_start[s] = N;
  }
}

// ---------------------------------------------------------------------------
// k_value: per segment, accumulate hv = relu(x@vW+vb)+x@vP over its rows
// (thread j owns channel j; vW/vP column j cached in registers), then fused
// segment res_block (v_out_W staged in LDS) + value head -> sval[s].
// ---------------------------------------------------------------------------
__global__ __launch_bounds__(128) void k_value(
    const float* __restrict__ x,
    const int* __restrict__ row_start,
    const float* __restrict__ vW, const float* __restrict__ vb,
    const float* __restrict__ vP,
    const float* __restrict__ voW, const float* __restrict__ vob,
    const float* __restrict__ vlW, const float* __restrict__ vlb,
    float* __restrict__ sval, int spb)
{
  __shared__ float voW_sh[DH * DH];
  __shared__ float x_sh[DIN];
  __shared__ float agg_sh[DH];
  __shared__ float red_sh[2];

  const int j = threadIdx.x;
  for (int i = j; i < DH * DH; i += 128) voW_sh[i] = voW[i];

  float wc[DIN], pc[DIN];
#pragma unroll
  for (int k = 0; k < DIN; ++k) {
    wc[k] = vW[k * DH + j];
    pc[k] = vP[k * DH + j];
  }
  const float bj   = vb[j];
  const float vobj = vob[j];
  const float vlwj = vlW[j];
  const float vlb0 = vlb[0];

  const int s0 = blockIdx.x * spb;
  const int s1 = min(s0 + spb, SEGS);
  __syncthreads();

  for (int s = s0; s < s1; ++s) {
    const int r0 = row_start[s];
    const int r1 = row_start[s + 1];
    if (r0 == r1) continue;  // empty segment: never gathered, skip

    float acc = 0.f;
    float xr = (j < DIN) ? x[(long long)r0 * DIN + j] : 0.f;  // prefetch row r0
    for (int r = r0; r < r1; ++r) {
      if (j < DIN) x_sh[j] = xr;
      __syncthreads();
      if (j < DIN && r + 1 < r1) xr = x[(long long)(r + 1) * DIN + j];  // prefetch next
      float h = bj, p = 0.f;
#pragma unroll
      for (int k4 = 0; k4 < DIN; k4 += 4) {
        float4 xv = *(const float4*)&x_sh[k4];
        h = fmaf(xv.x, wc[k4 + 0], h);  p = fmaf(xv.x, pc[k4 + 0], p);
        h = fmaf(xv.y, wc[k4 + 1], h);  p = fmaf(xv.y, pc[k4 + 1], p);
        h = fmaf(xv.z, wc[k4 + 2], h);  p = fmaf(xv.z, pc[k4 + 2], p);
        h = fmaf(xv.w, wc[k4 + 3], h);  p = fmaf(xv.w, pc[k4 + 3], p);
      }
      acc += fmaxf(h, 0.f) + p;
      __syncthreads();
    }

    // segment res_block + head
    agg_sh[j] = acc;
    __syncthreads();
    float h2a = vobj, h2b = 0.f;
#pragma unroll
    for (int k4 = 0; k4 < DH; k4 += 8) {
      float4 aA = *(const float4*)&agg_sh[k4];
      float4 aB = *(const float4*)&agg_sh[k4 + 4];
      h2a = fmaf(aA.x, voW_sh[(k4 + 0) * DH + j], h2a);
      h2a = fmaf(aA.y, voW_sh[(k4 + 1) * DH + j], h2a);
      h2a = fmaf(aA.z, voW_sh[(k4 + 2) * DH + j], h2a);
      h2a = fmaf(aA.w, voW_sh[(k4 + 3) * DH + j], h2a);
      h2b = fmaf(aB.x, voW_sh[(k4 + 4) * DH + j], h2b);
      h2b = fmaf(aB.y, voW_sh[(k4 + 5) * DH + j], h2b);
      h2b = fmaf(aB.z, voW_sh[(k4 + 6) * DH + j], h2b);
      h2b = fmaf(aB.w, voW_sh[(k4 + 7) * DH + j], h2b);
    }
    float h2 = fmaxf(h2a + h2b, 0.f) + acc;
    float part = h2 * vlwj;
#pragma unroll
    for (int o = 32; o > 0; o >>= 1) part += __shfl_xor(part, o);
    if ((j & 63) == 0) red_sh[j >> 6] = part;
    __syncthreads();
    if (j == 0) sval[s] = red_sh[0] + red_sh[1] + vlb0;
    __syncthreads();
  }
}

// ---------------------------------------------------------------------------
// k_adv: per segment, per row: a1 = relu(x@aW0+b0)+x@aP0 (reg weights),
// a2 = relu(a1@aW1+b1)+a1 (aW1 in LDS), adv = a2@alW+alb. Segment mean is
// accumulated in-block; out[r] = sval[s] + adv - mean, written in-place
// (out used as adv scratch, fixed up after the segment's rows are done).
// ---------------------------------------------------------------------------
__global__ __launch_bounds__(128) void k_adv(
    const float* __restrict__ x,
    const int* __restrict__ row_start,
    const float* __restrict__ aW0, const float* __restrict__ ab0,
    const float* __restrict__ aP0,
    const float* __restrict__ aW1, const float* __restrict__ ab1,
    const float* __restrict__ alW, const float* __restrict__ alb,
    const float* __restrict__ sval,
    float* __restrict__ out, int spb)
{
  __shared__ float aW1_sh[DH * DH];
  __shared__ float x_sh[DIN];
  __shared__ float a1_sh[DH];
  __shared__ float red_sh[2];

  const int j = threadIdx.x;
  for (int i = j; i < DH * DH; i += 128) aW1_sh[i] = aW1[i];

  float w0[DIN], p0[DIN];
#pragma unroll
  for (int k = 0; k < DIN; ++k) {
    w0[k] = aW0[k * DH + j];
    p0[k] = aP0[k * DH + j];
  }
  const float b0j  = ab0[j];
  const float b1j  = ab1[j];
  const float alwj = alW[j];
  const float alb0 = alb[0];

  const int s0 = blockIdx.x * spb;
  const int s1 = min(s0 + spb, SEGS);
  __syncthreads();

  for (int s = s0; s < s1; ++s) {
    const int r0 = row_start[s];
    const int r1 = row_start[s + 1];
    if (r0 == r1) continue;
    const float sv = sval[s];

    float advsum = 0.f;
    float xr = (j < DIN) ? x[(long long)r0 * DIN + j] : 0.f;
    for (int r = r0; r < r1; ++r) {
      if (j < DIN) x_sh[j] = xr;
      __syncthreads();
      if (j < DIN && r + 1 < r1) xr = x[(long long)(r + 1) * DIN + j];
      float h = b0j, p = 0.f;
#pragma unroll
      for (int k4 = 0; k4 < DIN; k4 += 4) {
        float4 xv = *(const float4*)&x_sh[k4];
        h = fmaf(xv.x, w0[k4 + 0], h);  p = fmaf(xv.x, p0[k4 + 0], p);
        h = fmaf(xv.y, w0[k4 + 1], h);  p = fmaf(xv.y, p0[k4 + 1], p);
        h = fmaf(xv.z, w0[k4 + 2], h);  p = fmaf(xv.z, p0[k4 + 2], p);
        h = fmaf(xv.w, w0[k4 + 3], h);  p = fmaf(xv.w, p0[k4 + 3], p);
      }
      const float a1 = fmaxf(h, 0.f) + p;
      a1_sh[j] = a1;
      __syncthreads();
      float c2a = b1j, c2b = 0.f;
#pragma unroll
      for (int k4 = 0; k4 < DH; k4 += 8) {
        float4 aA = *(const float4*)&a1_sh[k4];
        float4 aB = *(const float4*)&a1_sh[k4 + 4];
        c2a = fmaf(aA.x, aW1_sh[(k4 + 0) * DH + j], c2a);
        c2a = fmaf(aA.y, aW1_sh[(k4 + 1) * DH + j], c2a);
        c2a = fmaf(aA.z, aW1_sh[(k4 + 2) * DH + j], c2a);
        c2a = fmaf(aA.w, aW1_sh[(k4 + 3) * DH + j], c2a);
        c2b = fmaf(aB.x, aW1_sh[(k4 + 4) * DH + j], c2b);
        c2b = fmaf(aB.y, aW1_sh[(k4 + 5) * DH + j], c2b);
        c2b = fmaf(aB.z, aW1_sh[(k4 + 6) * DH + j], c2b);
        c2b = fmaf(aB.w, aW1_sh[(k4 + 7) * DH + j], c2b);
      }
      const float a2 = fmaxf(c2a + c2b, 0.f) + a1;
      float part = a2 * alwj;
#pragma unroll
      for (int o = 32; o > 0; o >>= 1) part += __shfl_xor(part, o);
      if ((j & 63) == 0) red_sh[j >> 6] = part;
      __syncthreads();
      const float adv = red_sh[0] + red_sh[1] + alb0;  // uniform on all threads
      advsum += adv;
      if (j == 0) out[r] = adv;  // adv scratch
      __syncthreads();
    }

    // fix-up: out[r] = sval + adv - mean   (syncthreads makes thread0's
    // global writes visible block-wide; all rows of s are owned by this block)
    const float corr = sv - advsum / (float)(r1 - r0);
    for (int r = r0 + j; r < r1; r += 128) out[r] += corr;
  }
}

// ---------------------------------------------------------------------------
// k_idx: second output = index, stored as float in out[N .. 2N)
// ---------------------------------------------------------------------------
__global__ void k_idx(const int* __restrict__ idx,
                      float* __restrict__ out, int N) {
  int i = blockIdx.x * blockDim.x + threadIdx.x;
  if (i < N) out[N + i] = (float)idx[i];
}

extern "C" void kernel_launch(void* const* d_in, const int* in_sizes, int n_in,
                              void* d_out, int out_size, void* d_ws, size_t ws_size,
                              hipStream_t stream) {
  (void)n_in; (void)out_size; (void)ws_size;
  const float* x   = (const float*)d_in[0];
  const int*   idx = (const int*)d_in[1];   // harness passes integer inputs as int32
  const float* vW  = (const float*)d_in[2];
  const float* vb  = (const float*)d_in[3];
  const float* vP  = (const float*)d_in[4];
  const float* voW = (const float*)d_in[5];
  const float* vob = (const float*)d_in[6];
  const float* vlW = (const float*)d_in[7];
  const float* vlb = (const float*)d_in[8];
  const float* aW0 = (const float*)d_in[9];
  const float* ab0 = (const float*)d_in[10];
  const float* aP0 = (const float*)d_in[11];
  const float* aW1 = (const float*)d_in[12];
  const float* ab1 = (const float*)d_in[13];
  const float* alW = (const float*)d_in[14];
  const float* alb = (const float*)d_in[15];

  const int N = in_sizes[0] / DIN;
  float* out = (float*)d_out;

  int*   row_start = (int*)d_ws;                  // SEGS+1 ints
  float* sval      = (float*)d_ws + (SEGS + 1);   // SEGS floats

  k_bounds<<<(N + 255) / 256, 256, 0, stream>>>(idx, row_start, N);

  const int spb  = 64;
  const int nblk = (SEGS + spb - 1) / spb;
  k_value<<<nblk, 128, 0, stream>>>(x, row_start, vW, vb, vP, voW, vob, vlW, vlb,
                                    sval, spb);
  k_adv<<<nblk, 128, 0, stream>>>(x, row_start, aW0, ab0, aP0, aW1, ab1, alW, alb,
                                  sval, out, spb);
  k_idx<<<(N + 255) / 256, 256, 0, stream>>>(idx, out, N);
}

// Round 3
// 753.251 us; speedup vs baseline: 8.4450x; 8.4450x over previous
//
#include <hip/hip_runtime.h>

typedef _Float16 f16;
typedef _Float16 f16x8 __attribute__((ext_vector_type(8)));
typedef float    f32x4 __attribute__((ext_vector_type(4)));

#define NROWS 1000000
#define DIN   64
#define DH    128
#define SEGS  250000
#define SPB   64   // segments per block

#define MFMA16(a, b, c) __builtin_amdgcn_mfma_f32_16x16x32_f16((a), (b), (c), 0, 0, 0)

// ---------------------------------------------------------------------------
// k_bounds: row_start[s] = first row r with index[r] >= s  (index sorted).
// ---------------------------------------------------------------------------
__global__ void k_bounds(const int* __restrict__ idx,
                         int* __restrict__ row_start, int N) {
  int r = blockIdx.x * blockDim.x + threadIdx.x;
  if (r >= N) return;
  int cur  = min(max(idx[r], 0), SEGS - 1);
  int prev = (r == 0) ? -1 : min(max(idx[r - 1], 0), SEGS - 1);
  for (int s = prev + 1; s <= cur; ++s) row_start[s] = r;
  if (r == N - 1) {
    for (int s = cur + 1; s <= SEGS; ++s) row_start[s] = N;
  }
}

// ---------------------------------------------------------------------------
// k_pack: W[K][128] f32 -> f16 B-fragments for mfma_f32_16x16x32_f16.
// Fragment f = cf*T + t (T = K/32); lane l, elem e  <->  W[k][c],
// k = t*32 + (l>>4)*8 + e,  c = cf*16 + (l&15). Flat: out[(f*64+l)*8+e].
// ---------------------------------------------------------------------------
__global__ void k_pack(const float* __restrict__ W, f16* __restrict__ out, int K) {
  const int T = K >> 5;
  int i = blockIdx.x * blockDim.x + threadIdx.x;
  if (i >= K * DH) return;
  int e = i & 7, l = (i >> 3) & 63, f = i >> 9;
  int t = f % T, cf = f / T;
  int k = t * 32 + ((l >> 4) << 3) + e;
  int c = cf * 16 + (l & 15);
  out[i] = (f16)W[k * DH + c];
}

__device__ inline f16x8 ldfrag(const f16* __restrict__ p, int f, int lane) {
  return *(const f16x8*)(p + (((size_t)f * 64 + lane) << 3));
}

__device__ inline f16x8 cvt8(f32x4 u0, f32x4 u1) {
  f16x8 r;
  r[0] = (f16)u0[0]; r[1] = (f16)u0[1]; r[2] = (f16)u0[2]; r[3] = (f16)u0[3];
  r[4] = (f16)u1[0]; r[5] = (f16)u1[1]; r[6] = (f16)u1[2]; r[7] = (f16)u1[3];
  return r;
}

// ---------------------------------------------------------------------------
// k_fused: block owns segments [s0, s0+64). Rows [row_start[s0], row_start[s0+64))
// processed in 64-row MFMA tiles. Wave w owns output cols [32w, 32w+32).
// ---------------------------------------------------------------------------
__global__ __launch_bounds__(256) void k_fused(
    const float* __restrict__ x, const int* __restrict__ idx,
    const int* __restrict__ row_start,
    const f16* __restrict__ vWp, const f16* __restrict__ vPp,
    const f16* __restrict__ aW0p, const f16* __restrict__ aP0p,
    const f16* __restrict__ aW1p, const f16* __restrict__ voWp,
    const float* __restrict__ vb,  const float* __restrict__ vob,
    const float* __restrict__ vlW, const float* __restrict__ vlb,
    const float* __restrict__ ab0, const float* __restrict__ ab1,
    const float* __restrict__ alW, const float* __restrict__ alb,
    float* __restrict__ out)
{
  __shared__ f16   Hsh[64 * DH];        // 16 KB  h (f16), row-major, no swizzle
  __shared__ f16   A1sh[64 * DH];       // 16 KB  a1 (f16), XOR-swizzled rows
  __shared__ float aggsh[SPB * DH];     // 32 KB  segment agg (f32), swizzled
  __shared__ float advp[4][64];         // cross-wave partial sums
  __shared__ float advsum_sh[SPB];
  __shared__ float corr_sh[SPB];
  __shared__ int   segsh[64];

  const int wave = threadIdx.x >> 6, lane = threadIdx.x & 63;
  const int lg = lane >> 4, lm = lane & 15;
  const int s0 = blockIdx.x * SPB;
  const int send = min(s0 + SPB, SEGS);
  const int rbeg = row_start[s0], rend = row_start[send];

  // persistent B-fragments (per wave: its 2 colfrags of each matrix)
  f16x8 bvW[2][2], bvP[2][2], bW0[2][2], bP0[2][2], bW1[2][4];
#pragma unroll
  for (int cf = 0; cf < 2; ++cf) {
    const int gcf = wave * 2 + cf;
#pragma unroll
    for (int t = 0; t < 2; ++t) {
      bvW[cf][t] = ldfrag(vWp,  gcf * 2 + t, lane);
      bvP[cf][t] = ldfrag(vPp,  gcf * 2 + t, lane);
      bW0[cf][t] = ldfrag(aW0p, gcf * 2 + t, lane);
      bP0[cf][t] = ldfrag(aP0p, gcf * 2 + t, lane);
    }
#pragma unroll
    for (int t = 0; t < 4; ++t) bW1[cf][t] = ldfrag(aW1p, gcf * 4 + t, lane);
  }

  const int c0 = (wave * 2 + 0) * 16 + lm, c1 = (wave * 2 + 1) * 16 + lm;
  const float vbr[2]  = {vb[c0], vb[c1]};
  const float ab0r[2] = {ab0[c0], ab0[c1]};
  const float ab1r[2] = {ab1[c0], ab1[c1]};
  const float vobr[2] = {vob[c0], vob[c1]};
  const float alwr[2] = {alW[c0], alW[c1]};
  const float vlwr[2] = {vlW[c0], vlW[c1]};
  const float alb0 = alb[0], vlb0 = vlb[0];

  for (int i = threadIdx.x; i < SPB * DH; i += 256) aggsh[i] = 0.f;
  if (threadIdx.x < SPB) advsum_sh[threadIdx.x] = 0.f;
  __syncthreads();

  // ---------------- tile loop over this block's rows ----------------
  for (int rt = rbeg; rt < rend; rt += 64) {
    const int nrows = min(64, rend - rt);
    if (threadIdx.x < 64)
      segsh[threadIdx.x] = (threadIdx.x < nrows) ? (idx[rt + threadIdx.x] - s0) : -1;

    // X A-fragments straight from global (f32 -> f16)
    f16x8 ax[4][2];
#pragma unroll
    for (int rf = 0; rf < 4; ++rf) {
      const int row = rf * 16 + lm;
      const float* px = x + (size_t)(rt + row) * DIN + lg * 8;
#pragma unroll
      for (int t = 0; t < 2; ++t) {
        f32x4 u0 = {0.f, 0.f, 0.f, 0.f}, u1 = {0.f, 0.f, 0.f, 0.f};
        if (row < nrows) {
          u0 = *(const f32x4*)(px + t * 32);
          u1 = *(const f32x4*)(px + t * 32 + 4);
        }
        ax[rf][t] = cvt8(u0, u1);
      }
    }

    // ---- phase V: h = relu(x@vW+vb) + x@vP  -> Hsh (f16) ----
    {
      f32x4 cA[4][2], cB[4][2];
#pragma unroll
      for (int rf = 0; rf < 4; ++rf)
#pragma unroll
        for (int cf = 0; cf < 2; ++cf) {
          f32x4 z = {0.f, 0.f, 0.f, 0.f};
          cA[rf][cf] = z; cB[rf][cf] = z;
        }
#pragma unroll
      for (int t = 0; t < 2; ++t)
#pragma unroll
        for (int rf = 0; rf < 4; ++rf)
#pragma unroll
          for (int cf = 0; cf < 2; ++cf) {
            cA[rf][cf] = MFMA16(ax[rf][t], bvW[cf][t], cA[rf][cf]);
            cB[rf][cf] = MFMA16(ax[rf][t], bvP[cf][t], cB[rf][cf]);
          }
#pragma unroll
      for (int rf = 0; rf < 4; ++rf)
#pragma unroll
        for (int cf = 0; cf < 2; ++cf) {
          const int col = (wave * 2 + cf) * 16 + lm;
#pragma unroll
          for (int q = 0; q < 4; ++q) {
            const int row = rf * 16 + lg * 4 + q;
            float hv = fmaxf(cA[rf][cf][q] + vbr[cf], 0.f) + cB[rf][cf][q];
            Hsh[row * DH + col] = (f16)hv;
          }
        }
    }

    // ---- phase A: a1 = relu(x@aW0+ab0) + x@aP0 -> regs + A1sh (swizzled) ----
    f32x4 a1r[4][2];
    {
      f32x4 cA[4][2], cB[4][2];
#pragma unroll
      for (int rf = 0; rf < 4; ++rf)
#pragma unroll
        for (int cf = 0; cf < 2; ++cf) {
          f32x4 z = {0.f, 0.f, 0.f, 0.f};
          cA[rf][cf] = z; cB[rf][cf] = z;
        }
#pragma unroll
      for (int t = 0; t < 2; ++t)
#pragma unroll
        for (int rf = 0; rf < 4; ++rf)
#pragma unroll
          for (int cf = 0; cf < 2; ++cf) {
            cA[rf][cf] = MFMA16(ax[rf][t], bW0[cf][t], cA[rf][cf]);
            cB[rf][cf] = MFMA16(ax[rf][t], bP0[cf][t], cB[rf][cf]);
          }
#pragma unroll
      for (int rf = 0; rf < 4; ++rf)
#pragma unroll
        for (int cf = 0; cf < 2; ++cf) {
          const int col = (wave * 2 + cf) * 16 + lm;
#pragma unroll
          for (int q = 0; q < 4; ++q) {
            const int row = rf * 16 + lg * 4 + q;
            float a1 = fmaxf(cA[rf][cf][q] + ab0r[cf], 0.f) + cB[rf][cf][q];
            a1r[rf][cf][q] = a1;
            const int ad = (row * 256 + col * 2) ^ ((row & 7) << 4);
            *(f16*)((char*)A1sh + ad) = (f16)a1;
          }
        }
    }
    __syncthreads();  // B1: A1sh ready

    // ---- GEMM2: a2 = relu(a1@aW1+ab1) + a1; adv partials ----
    {
      f32x4 c2[4][2];
#pragma unroll
      for (int rf = 0; rf < 4; ++rf)
#pragma unroll
        for (int cf = 0; cf < 2; ++cf) {
          f32x4 z = {0.f, 0.f, 0.f, 0.f};
          c2[rf][cf] = z;
        }
#pragma unroll
      for (int rf = 0; rf < 4; ++rf) {
        const int row = rf * 16 + lm;
#pragma unroll
        for (int t = 0; t < 4; ++t) {
          const int ad = (row * 256 + t * 64 + lg * 16) ^ ((row & 7) << 4);
          f16x8 av = *(const f16x8*)((const char*)A1sh + ad);
#pragma unroll
          for (int cf = 0; cf < 2; ++cf)
            c2[rf][cf] = MFMA16(av, bW1[cf][t], c2[rf][cf]);
        }
      }
      f32x4 p[4];
#pragma unroll
      for (int rf = 0; rf < 4; ++rf)
#pragma unroll
        for (int q = 0; q < 4; ++q) {
          float a2_0 = fmaxf(c2[rf][0][q] + ab1r[0], 0.f) + a1r[rf][0][q];
          float a2_1 = fmaxf(c2[rf][1][q] + ab1r[1], 0.f) + a1r[rf][1][q];
          p[rf][q] = a2_0 * alwr[0] + a2_1 * alwr[1];
        }
#pragma unroll
      for (int m = 1; m <= 8; m <<= 1)
#pragma unroll
        for (int rf = 0; rf < 4; ++rf)
#pragma unroll
          for (int q = 0; q < 4; ++q)
            p[rf][q] += __shfl_xor(p[rf][q], m);
      if (lm == 0) {
#pragma unroll
        for (int rf = 0; rf < 4; ++rf)
          *(f32x4*)&advp[wave][rf * 16 + lg * 4] = p[rf];
      }
    }
    __syncthreads();  // B2: Hsh + advp ready

    // ---- epilogue role split ----
    if (threadIdx.x < 128) {          // per-channel segment run-reduce of h
      const int ch = threadIdx.x;
      float run = 0.f;
      int sprev = segsh[0];
      for (int r = 0; r < nrows; ++r) {
        int s = segsh[r];
        float hv = (float)Hsh[r * DH + ch];
        if (s != sprev) {
          const int ad = (sprev * 512 + ch * 4) ^ ((sprev & 7) << 4);
          *(float*)((char*)aggsh + ad) += run;
          run = 0.f; sprev = s;
        }
        run += hv;
      }
      {
        const int ad = (sprev * 512 + ch * 4) ^ ((sprev & 7) << 4);
        *(float*)((char*)aggsh + ad) += run;
      }
    } else if (wave == 2) {           // adv: cross-wave sum + segmented suffix scan
      const int r = lane;
      const bool valid = r < nrows;
      const int s = valid ? segsh[r] : -1;
      float acc = 0.f;
      if (valid) {
        float adv = advp[0][r] + advp[1][r] + advp[2][r] + advp[3][r] + alb0;
        out[rt + r] = adv;            // adv scratch; corr added later
        acc = adv;
      }
#pragma unroll
      for (int d = 1; d < 64; d <<= 1) {
        float nv = __shfl_down(acc, d);
        int   ns = __shfl_down(s, d);
        if (r + d < 64 && ns == s) acc += nv;
      }
      bool head = valid && (r == 0 || segsh[r - 1] != s);
      if (head) advsum_sh[s] += acc;
    }
    __syncthreads();  // B3: LDS reusable next tile
  }

  // ---------------- stage 2: segment res_block + value head ----------------
  {
    f16x8 bvo[2][4];
#pragma unroll
    for (int cf = 0; cf < 2; ++cf)
#pragma unroll
      for (int t = 0; t < 4; ++t)
        bvo[cf][t] = ldfrag(voWp, (wave * 2 + cf) * 4 + t, lane);

    f32x4 c2[4][2];
#pragma unroll
    for (int rf = 0; rf < 4; ++rf)
#pragma unroll
      for (int cf = 0; cf < 2; ++cf) {
        f32x4 z = {0.f, 0.f, 0.f, 0.f};
        c2[rf][cf] = z;
      }
#pragma unroll
    for (int rf = 0; rf < 4; ++rf) {
      const int row = rf * 16 + lm;
#pragma unroll
      for (int t = 0; t < 4; ++t) {
        const int base = row * 512 + t * 128 + lg * 32;
        f32x4 u0 = *(const f32x4*)((const char*)aggsh + ((base) ^ ((row & 7) << 4)));
        f32x4 u1 = *(const f32x4*)((const char*)aggsh + ((base + 16) ^ ((row & 7) << 4)));
        f16x8 av = cvt8(u0, u1);
#pragma unroll
        for (int cf = 0; cf < 2; ++cf)
          c2[rf][cf] = MFMA16(av, bvo[cf][t], c2[rf][cf]);
      }
    }
    f32x4 p[4];
#pragma unroll
    for (int rf = 0; rf < 4; ++rf)
#pragma unroll
      for (int q = 0; q < 4; ++q) {
        const int row = rf * 16 + lg * 4 + q;
        float h2s = 0.f;
#pragma unroll
        for (int cf = 0; cf < 2; ++cf) {
          const int col = (wave * 2 + cf) * 16 + lm;
          const int ad = (row * 512 + col * 4) ^ ((row & 7) << 4);
          float agv = *(const float*)((const char*)aggsh + ad);
          float h2 = fmaxf(c2[rf][cf][q] + vobr[cf], 0.f) + agv;
          h2s += h2 * vlwr[cf];
        }
        p[rf][q] = h2s;
      }
#pragma unroll
    for (int m = 1; m <= 8; m <<= 1)
#pragma unroll
      for (int rf = 0; rf < 4; ++rf)
#pragma unroll
        for (int q = 0; q < 4; ++q)
          p[rf][q] += __shfl_xor(p[rf][q], m);
    if (lm == 0) {
#pragma unroll
      for (int rf = 0; rf < 4; ++rf)
        *(f32x4*)&advp[wave][rf * 16 + lg * 4] = p[rf];
    }
  }
  __syncthreads();

  if (threadIdx.x < send - s0) {
    const int sl = threadIdx.x;
    float sv = advp[0][sl] + advp[1][sl] + advp[2][sl] + advp[3][sl] + vlb0;
    int cnt = row_start[s0 + sl + 1] - row_start[s0 + sl];
    corr_sh[sl] = sv - advsum_sh[sl] / (float)max(cnt, 1);
  }
  __syncthreads();

  for (int r = rbeg + threadIdx.x; r < rend; r += 256) {
    int s = idx[r];
    out[r] = out[r] + corr_sh[s - s0];
    out[NROWS + r] = (float)s;
  }
}

extern "C" void kernel_launch(void* const* d_in, const int* in_sizes, int n_in,
                              void* d_out, int out_size, void* d_ws, size_t ws_size,
                              hipStream_t stream) {
  (void)n_in; (void)out_size; (void)ws_size;
  const float* x   = (const float*)d_in[0];
  const int*   idx = (const int*)d_in[1];
  const float* vW  = (const float*)d_in[2];
  const float* vb  = (const float*)d_in[3];
  const float* vP  = (const float*)d_in[4];
  const float* voW = (const float*)d_in[5];
  const float* vob = (const float*)d_in[6];
  const float* vlW = (const float*)d_in[7];
  const float* vlb = (const float*)d_in[8];
  const float* aW0 = (const float*)d_in[9];
  const float* ab0 = (const float*)d_in[10];
  const float* aP0 = (const float*)d_in[11];
  const float* aW1 = (const float*)d_in[12];
  const float* ab1 = (const float*)d_in[13];
  const float* alW = (const float*)d_in[14];
  const float* alb = (const float*)d_in[15];

  const int N = in_sizes[0] / DIN;
  float* out = (float*)d_out;

  int* row_start = (int*)d_ws;                                  // SEGS+1 ints
  char* pkbase = (char*)d_ws + (((SEGS + 1) * 4 + 127) & ~127);
  f16* vWp  = (f16*)pkbase;          // 8192 each for K=64 matrices
  f16* vPp  = vWp  + 8192;
  f16* aW0p = vPp  + 8192;
  f16* aP0p = aW0p + 8192;
  f16* aW1p = aP0p + 8192;           // 16384 (K=128)
  f16* voWp = aW1p + 16384;          // 16384

  k_bounds<<<(N + 255) / 256, 256, 0, stream>>>(idx, row_start, N);
  k_pack<<<32, 256, 0, stream>>>(vW,  vWp,  64);
  k_pack<<<32, 256, 0, stream>>>(vP,  vPp,  64);
  k_pack<<<32, 256, 0, stream>>>(aW0, aW0p, 64);
  k_pack<<<32, 256, 0, stream>>>(aP0, aP0p, 64);
  k_pack<<<64, 256, 0, stream>>>(aW1, aW1p, 128);
  k_pack<<<64, 256, 0, stream>>>(voW, voWp, 128);

  const int nblk = (SEGS + SPB - 1) / SPB;
  k_fused<<<nblk, 256, 0, stream>>>(x, idx, row_start,
                                    vWp, vPp, aW0p, aP0p, aW1p, voWp,
                                    vb, vob, vlW, vlb, ab0, ab1, alW, alb,
                                    out);
}

// Round 4
// 479.648 us; speedup vs baseline: 13.2622x; 1.5704x over previous
//
#include <hip/hip_runtime.h>

typedef _Float16 f16;
typedef _Float16 f16x8 __attribute__((ext_vector_type(8)));
typedef _Float16 f16x4v __attribute__((ext_vector_type(4)));
typedef float    f32x4 __attribute__((ext_vector_type(4)));
typedef int      i32x4 __attribute__((ext_vector_type(4)));

#define NROWS 1000000
#define DIN   64
#define DH    128
#define SEGS  250000
#define SPB   64

#define MFMA16(a, b, c) __builtin_amdgcn_mfma_f32_16x16x32_f16((a), (b), (c), 0, 0, 0)

// ---------------------------------------------------------------------------
// k_bounds: row_start[s] = first row r with index[r] >= s  (index sorted).
// ---------------------------------------------------------------------------
__global__ void k_bounds(const int* __restrict__ idx,
                         int* __restrict__ row_start, int N) {
  int r = blockIdx.x * blockDim.x + threadIdx.x;
  if (r >= N) return;
  int cur  = min(max(idx[r], 0), SEGS - 1);
  int prev = (r == 0) ? -1 : min(max(idx[r - 1], 0), SEGS - 1);
  for (int s = prev + 1; s <= cur; ++s) row_start[s] = r;
  if (r == N - 1) {
    for (int s = cur + 1; s <= SEGS; ++s) row_start[s] = N;
  }
}

// ---------------------------------------------------------------------------
// k_pack: W[K][128] f32 -> f16 fragments for mfma_f32_16x16x32_f16.
// Lane l, elem e of frag f = cb*T + t (T=K/32):  k = t*32+(l>>4)*8+e,
// c = cb*16+(l&15), value = W[k][c].  These bytes serve BOTH as B-frags of W
// and as A-frags of W^T (A/B lane layouts are symmetric).
// ---------------------------------------------------------------------------
__global__ void k_pack(const float* __restrict__ W, f16* __restrict__ out, int K) {
  const int T = K >> 5;
  int i = blockIdx.x * blockDim.x + threadIdx.x;
  if (i >= K * DH) return;
  int e = i & 7, l = (i >> 3) & 63, f = i >> 9;
  int t = f % T, cb = f / T;
  int k = t * 32 + ((l >> 4) << 3) + e;
  int c = cb * 16 + (l & 15);
  out[i] = (f16)W[k * DH + c];
}

__device__ inline f16x8 ldfrag(const f16* __restrict__ p, int f, int lane) {
  return *(const f16x8*)(p + (((size_t)f * 64 + lane) << 3));
}

__device__ inline f16x8 cvt8(f32x4 u0, f32x4 u1) {
  f16x8 r;
  r[0] = (f16)u0[0]; r[1] = (f16)u0[1]; r[2] = (f16)u0[2]; r[3] = (f16)u0[3];
  r[4] = (f16)u1[0]; r[5] = (f16)u1[1]; r[6] = (f16)u1[2]; r[7] = (f16)u1[3];
  return r;
}

// ---------------------------------------------------------------------------
// k_fused: block owns segments [s0, s0+64), rows [row_start[s0], row_start[s0+64)).
// 64-row MFMA tiles; wave w owns ch-block [32w, 32w+32).
// agg (segment sums of h) accumulated via one-hot-indicator MFMA into C-frags.
// ---------------------------------------------------------------------------
__global__ __launch_bounds__(256) void k_fused(
    const float* __restrict__ x, const int* __restrict__ idx,
    const int* __restrict__ row_start,
    const f16* __restrict__ vWp, const f16* __restrict__ vPp,
    const f16* __restrict__ aW0p, const f16* __restrict__ aP0p,
    const f16* __restrict__ aW1p, const f16* __restrict__ voWp,
    const float* __restrict__ vb,  const float* __restrict__ vob,
    const float* __restrict__ vlW, const float* __restrict__ vlb,
    const float* __restrict__ ab0, const float* __restrict__ ab1,
    const float* __restrict__ alW, const float* __restrict__ alb,
    float* __restrict__ out)
{
  __shared__ __align__(16) f16  Hsh[16 * 512];   // h B-frags, wave-private quadrants (16 KB)
  __shared__ __align__(16) f16  Ash[16 * 512];   // a1 A-frags / stage-2 agg A-frags (16 KB)
  __shared__ __align__(16) int  segsh[2][64];
  __shared__ __align__(16) float advp[4][64];
  __shared__ float advsum_sh[SPB];
  __shared__ float corr_sh[SPB];

  const int tid  = threadIdx.x;
  const int wave = tid >> 6, lane = tid & 63;
  const int lg = lane >> 4, lm = lane & 15;
  const int s0 = blockIdx.x * SPB;
  const int send = min(s0 + SPB, SEGS);
  const int rbeg = row_start[s0], rend = row_start[send];

  // per-lane bias/head scalars, transposed-layout (ch = wave*32 + i*16 + lg*4 + q)
  float b0r[2][4], b1r[2][4], alwr[2][4];
#pragma unroll
  for (int i = 0; i < 2; ++i)
#pragma unroll
    for (int q = 0; q < 4; ++q) {
      const int ch = wave * 32 + i * 16 + lg * 4 + q;
      b0r[i][q] = ab0[ch]; b1r[i][q] = ab1[ch]; alwr[i][q] = alW[ch];
    }
  // C-layout scalars (ch = wave*32 + cf*16 + lm)
  const int cc0 = wave * 32 + lm, cc1 = cc0 + 16;
  const float vbr[2]  = {vb[cc0],  vb[cc1]};
  const float vobr[2] = {vob[cc0], vob[cc1]};
  const float vlwr[2] = {vlW[cc0], vlW[cc1]};
  const float alb0 = alb[0], vlb0 = vlb[0];

  f32x4 agg_c[4][2];
#pragma unroll
  for (int rf = 0; rf < 4; ++rf)
#pragma unroll
    for (int cf = 0; cf < 2; ++cf) { f32x4 z = {0.f,0.f,0.f,0.f}; agg_c[rf][cf] = z; }

  if (tid < SPB) advsum_sh[tid] = 0.f;

  int par = 0;
  for (int rt = rbeg; rt < rend; rt += 64, par ^= 1) {
    const int nrows = min(64, rend - rt);
    if (tid < 64) segsh[par][tid] = (tid < nrows) ? (idx[rt + tid] - s0) : -1;
    __syncthreads();                                            // B0

    // x fragments (serve as A of x AND B of x^T)
    f16x8 ax[4][2];
#pragma unroll
    for (int rf = 0; rf < 4; ++rf) {
      const int row = rf * 16 + lm;
      const float* px = x + (size_t)(rt + row) * DIN + lg * 8;
#pragma unroll
      for (int t = 0; t < 2; ++t) {
        f32x4 u0 = {0.f,0.f,0.f,0.f}, u1 = {0.f,0.f,0.f,0.f};
        if (row < nrows) { u0 = *(const f32x4*)(px + t * 32); u1 = *(const f32x4*)(px + t * 32 + 4); }
        ax[rf][t] = cvt8(u0, u1);
      }
    }

    // ---- phase V: h = relu(x@vW+vb) + x@vP -> Hsh in B-frag layout (b64 stores) ----
    {
      f16x8 bW[2][2], bP[2][2];
#pragma unroll
      for (int cf = 0; cf < 2; ++cf)
#pragma unroll
        for (int t = 0; t < 2; ++t) {
          bW[cf][t] = ldfrag(vWp, (wave * 2 + cf) * 2 + t, lane);
          bP[cf][t] = ldfrag(vPp, (wave * 2 + cf) * 2 + t, lane);
        }
      f32x4 cA[4][2], cB[4][2];
#pragma unroll
      for (int rf = 0; rf < 4; ++rf)
#pragma unroll
        for (int cf = 0; cf < 2; ++cf) { f32x4 z = {0.f,0.f,0.f,0.f}; cA[rf][cf] = z; cB[rf][cf] = z; }
#pragma unroll
      for (int t = 0; t < 2; ++t)
#pragma unroll
        for (int rf = 0; rf < 4; ++rf)
#pragma unroll
          for (int cf = 0; cf < 2; ++cf) {
            cA[rf][cf] = MFMA16(ax[rf][t], bW[cf][t], cA[rf][cf]);
            cB[rf][cf] = MFMA16(ax[rf][t], bP[cf][t], cB[rf][cf]);
          }
#pragma unroll
      for (int rf = 0; rf < 4; ++rf)
#pragma unroll
        for (int cf = 0; cf < 2; ++cf) {
          f16x4v hv;
#pragma unroll
          for (int q = 0; q < 4; ++q)
            hv[q] = (f16)(fmaxf(cA[rf][cf][q] + vbr[cf], 0.f) + cB[rf][cf][q]);
          const int laneb = ((rf & 1) * 2 + (lg >> 1)) * 16 + lm;
          const int off = ((wave * 4 + cf * 2 + (rf >> 1)) * 64 + laneb) * 8 + (lg & 1) * 4;
          *(f16x4v*)&Hsh[off] = hv;
        }
    }

    // ---- phase A' (transposed): a1^T = relu(W0^T@x^T + b0) + P0^T@x^T ----
    float pA[4] = {0.f, 0.f, 0.f, 0.f};   // per-row residual dot  sum_ch a1*alW
    {
      f16x8 w0t[2][2], p0t[2][2];
#pragma unroll
      for (int rfc = 0; rfc < 2; ++rfc)
#pragma unroll
        for (int t = 0; t < 2; ++t) {
          w0t[rfc][t] = ldfrag(aW0p, (wave * 2 + rfc) * 2 + t, lane);
          p0t[rfc][t] = ldfrag(aP0p, (wave * 2 + rfc) * 2 + t, lane);
        }
      f32x4 cA2[2][4], cB2[2][4];
#pragma unroll
      for (int rfc = 0; rfc < 2; ++rfc)
#pragma unroll
        for (int cfr = 0; cfr < 4; ++cfr) { f32x4 z = {0.f,0.f,0.f,0.f}; cA2[rfc][cfr] = z; cB2[rfc][cfr] = z; }
#pragma unroll
      for (int t = 0; t < 2; ++t)
#pragma unroll
        for (int rfc = 0; rfc < 2; ++rfc)
#pragma unroll
          for (int cfr = 0; cfr < 4; ++cfr) {
            cA2[rfc][cfr] = MFMA16(w0t[rfc][t], ax[cfr][t], cA2[rfc][cfr]);
            cB2[rfc][cfr] = MFMA16(p0t[rfc][t], ax[cfr][t], cB2[rfc][cfr]);
          }
#pragma unroll
      for (int rfc = 0; rfc < 2; ++rfc)
#pragma unroll
        for (int cfr = 0; cfr < 4; ++cfr) {
          f16x4v av;
#pragma unroll
          for (int q = 0; q < 4; ++q) {
            float a1 = fmaxf(cA2[rfc][cfr][q] + b0r[rfc][q], 0.f) + cB2[rfc][cfr][q];
            pA[cfr] += a1 * alwr[rfc][q];
            av[q] = (f16)a1;
          }
          const int lane_a = lm + 16 * (rfc * 2 + (lg >> 1));
          const int off = ((cfr * 4 + wave) * 64 + lane_a) * 8 + (lg & 1) * 4;
          *(f16x4v*)&Ash[off] = av;
        }
    }

    // ---- agg += I @ H  (one-hot indicator in registers) ----
    {
      f16x8 hb[2][2];
#pragma unroll
      for (int cf = 0; cf < 2; ++cf)
#pragma unroll
        for (int t = 0; t < 2; ++t)
          hb[cf][t] = *(const f16x8*)&Hsh[((wave * 4 + cf * 2 + t) * 64 + lane) * 8];
#pragma unroll
      for (int t = 0; t < 2; ++t) {
        const i32x4 sa = *(const i32x4*)&segsh[par][t * 32 + lg * 8];
        const i32x4 sb = *(const i32x4*)&segsh[par][t * 32 + lg * 8 + 4];
#pragma unroll
        for (int rf = 0; rf < 4; ++rf) {
          const int tgt = rf * 16 + lm;
          f16x8 ind;
#pragma unroll
          for (int e = 0; e < 4; ++e) {
            ind[e]     = (sa[e] == tgt) ? (f16)1.f : (f16)0.f;
            ind[e + 4] = (sb[e] == tgt) ? (f16)1.f : (f16)0.f;
          }
#pragma unroll
          for (int cf = 0; cf < 2; ++cf)
            agg_c[rf][cf] = MFMA16(ind, hb[cf][t], agg_c[rf][cf]);
        }
      }
    }

    __syncthreads();                                            // B1: Ash ready

    // ---- GEMM2^T: relu(W1^T@a1^T + b1)·alW  (+pA) -> per-row adv partials ----
    {
      f16x8 w1[2][4];
#pragma unroll
      for (int rfc = 0; rfc < 2; ++rfc)
#pragma unroll
        for (int t = 0; t < 4; ++t)
          w1[rfc][t] = ldfrag(aW1p, (wave * 2 + rfc) * 4 + t, lane);
      f32x4 c2[2][4];
#pragma unroll
      for (int rfc = 0; rfc < 2; ++rfc)
#pragma unroll
        for (int cfr = 0; cfr < 4; ++cfr) { f32x4 z = {0.f,0.f,0.f,0.f}; c2[rfc][cfr] = z; }
#pragma unroll
      for (int t = 0; t < 4; ++t)
#pragma unroll
        for (int cfr = 0; cfr < 4; ++cfr) {
          const f16x8 bv = *(const f16x8*)&Ash[((cfr * 4 + t) * 64 + lane) * 8];
#pragma unroll
          for (int rfc = 0; rfc < 2; ++rfc)
            c2[rfc][cfr] = MFMA16(w1[rfc][t], bv, c2[rfc][cfr]);
        }
#pragma unroll
      for (int cfr = 0; cfr < 4; ++cfr) {
        float s = pA[cfr];
#pragma unroll
        for (int rfc = 0; rfc < 2; ++rfc)
#pragma unroll
          for (int q = 0; q < 4; ++q)
            s += fmaxf(c2[rfc][cfr][q] + b1r[rfc][q], 0.f) * alwr[rfc][q];
        s += __shfl_xor(s, 16);
        s += __shfl_xor(s, 32);
        if (lg == 0) advp[wave][cfr * 16 + lm] = s;
      }
    }
    __syncthreads();                                            // B2: advp ready

    if (wave == 2) {   // finalize: adv out + segmented scan -> advsum
      const int r = lane;
      const bool valid = r < nrows;
      const int sg = valid ? segsh[par][r] : -1;
      float acc = 0.f;
      if (valid) {
        float adv = advp[0][r] + advp[1][r] + advp[2][r] + advp[3][r] + alb0;
        out[rt + r] = adv;
        acc = adv;
      }
#pragma unroll
      for (int d = 1; d < 64; d <<= 1) {
        float nv = __shfl_down(acc, d);
        int   ns = __shfl_down(sg, d);
        if (r + d < 64 && ns == sg) acc += nv;
      }
      if (valid && (r == 0 || segsh[par][r - 1] != sg)) advsum_sh[sg] += acc;
    }
  }  // tile loop

  // ---------------- stage 2: segment res_block + value head ----------------
  __syncthreads();
  // agg C-frags -> Ash in A-frag layout (f16), once per block
#pragma unroll
  for (int rf = 0; rf < 4; ++rf)
#pragma unroll
    for (int cf = 0; cf < 2; ++cf) {
      const int hi = 16 * (cf * 2 + (lm >> 3));
#pragma unroll
      for (int q = 0; q < 4; ++q)
        Ash[((rf * 4 + wave) * 64 + (lg * 4 + q) + hi) * 8 + (lm & 7)] = (f16)agg_c[rf][cf][q];
    }
  __syncthreads();

  {
    f16x8 bvo[2][4];
#pragma unroll
    for (int cf = 0; cf < 2; ++cf)
#pragma unroll
      for (int t = 0; t < 4; ++t)
        bvo[cf][t] = ldfrag(voWp, (wave * 2 + cf) * 4 + t, lane);
    f32x4 c3[4][2];
#pragma unroll
    for (int rf = 0; rf < 4; ++rf)
#pragma unroll
      for (int cf = 0; cf < 2; ++cf) { f32x4 z = {0.f,0.f,0.f,0.f}; c3[rf][cf] = z; }
#pragma unroll
    for (int rf = 0; rf < 4; ++rf)
#pragma unroll
      for (int t = 0; t < 4; ++t) {
        const f16x8 av = *(const f16x8*)&Ash[((rf * 4 + t) * 64 + lane) * 8];
#pragma unroll
        for (int cf = 0; cf < 2; ++cf)
          c3[rf][cf] = MFMA16(av, bvo[cf][t], c3[rf][cf]);
      }
    f32x4 p3[4];
#pragma unroll
    for (int rf = 0; rf < 4; ++rf)
#pragma unroll
      for (int q = 0; q < 4; ++q) {
        float s = 0.f;
#pragma unroll
        for (int cf = 0; cf < 2; ++cf) {
          float h2 = fmaxf(c3[rf][cf][q] + vobr[cf], 0.f) + agg_c[rf][cf][q];
          s += h2 * vlwr[cf];
        }
        p3[rf][q] = s;
      }
#pragma unroll
    for (int m = 1; m <= 8; m <<= 1)
#pragma unroll
      for (int rf = 0; rf < 4; ++rf)
#pragma unroll
        for (int q = 0; q < 4; ++q)
          p3[rf][q] += __shfl_xor(p3[rf][q], m);
    if (lm == 0) {
#pragma unroll
      for (int rf = 0; rf < 4; ++rf)
        *(f32x4*)&advp[wave][rf * 16 + lg * 4] = p3[rf];
    }
  }
  __syncthreads();

  if (tid < send - s0) {
    float sv = advp[0][tid] + advp[1][tid] + advp[2][tid] + advp[3][tid] + vlb0;
    int cnt = row_start[s0 + tid + 1] - row_start[s0 + tid];
    corr_sh[tid] = sv - advsum_sh[tid] / (float)max(cnt, 1);
  }
  __syncthreads();

  for (int r = rbeg + tid; r < rend; r += 256) {
    const int s = idx[r];
    out[r] += corr_sh[s - s0];
    out[NROWS + r] = (float)s;
  }
}

extern "C" void kernel_launch(void* const* d_in, const int* in_sizes, int n_in,
                              void* d_out, int out_size, void* d_ws, size_t ws_size,
                              hipStream_t stream) {
  (void)n_in; (void)out_size; (void)ws_size;
  const float* x   = (const float*)d_in[0];
  const int*   idx = (const int*)d_in[1];
  const float* vW  = (const float*)d_in[2];
  const float* vb  = (const float*)d_in[3];
  const float* vP  = (const float*)d_in[4];
  const float* voW = (const float*)d_in[5];
  const float* vob = (const float*)d_in[6];
  const float* vlW = (const float*)d_in[7];
  const float* vlb = (const float*)d_in[8];
  const float* aW0 = (const float*)d_in[9];
  const float* ab0 = (const float*)d_in[10];
  const float* aP0 = (const float*)d_in[11];
  const float* aW1 = (const float*)d_in[12];
  const float* ab1 = (const float*)d_in[13];
  const float* alW = (const float*)d_in[14];
  const float* alb = (const float*)d_in[15];

  const int N = in_sizes[0] / DIN;
  float* out = (float*)d_out;

  int* row_start = (int*)d_ws;                                  // SEGS+1 ints
  char* pkbase = (char*)d_ws + (((SEGS + 1) * 4 + 127) & ~127);
  f16* vWp  = (f16*)pkbase;
  f16* vPp  = vWp  + 8192;
  f16* aW0p = vPp  + 8192;
  f16* aP0p = aW0p + 8192;
  f16* aW1p = aP0p + 8192;
  f16* voWp = aW1p + 16384;

  k_bounds<<<(N + 255) / 256, 256, 0, stream>>>(idx, row_start, N);
  k_pack<<<32, 256, 0, stream>>>(vW,  vWp,  64);
  k_pack<<<32, 256, 0, stream>>>(vP,  vPp,  64);
  k_pack<<<32, 256, 0, stream>>>(aW0, aW0p, 64);
  k_pack<<<32, 256, 0, stream>>>(aP0, aP0p, 64);
  k_pack<<<64, 256, 0, stream>>>(aW1, aW1p, 128);
  k_pack<<<64, 256, 0, stream>>>(voW, voWp, 128);

  const int nblk = (SEGS + SPB - 1) / SPB;
  k_fused<<<nblk, 256, 0, stream>>>(x, idx, row_start,
                                    vWp, vPp, aW0p, aP0p, aW1p, voWp,
                                    vb, vob, vlW, vlb, ab0, ab1, alW, alb,
                                    out);
}

// Round 5
// 450.485 us; speedup vs baseline: 14.1208x; 1.0647x over previous
//
#include <hip/hip_runtime.h>

typedef _Float16 f16;
typedef _Float16 f16x8 __attribute__((ext_vector_type(8)));
typedef _Float16 f16x4v __attribute__((ext_vector_type(4)));
typedef float    f32x4 __attribute__((ext_vector_type(4)));
typedef int      i32x4 __attribute__((ext_vector_type(4)));

#define NROWS 1000000
#define DIN   64
#define DH    128
#define SEGS  250000
#define SPB   64

#define MFMA16(a, b, c) __builtin_amdgcn_mfma_f32_16x16x32_f16((a), (b), (c), 0, 0, 0)

typedef __attribute__((address_space(1))) const void gas_t;
typedef __attribute__((address_space(3))) void las_t;
#define GLOAD_LDS16(gp, lp) \
  __builtin_amdgcn_global_load_lds((gas_t*)(gp), (las_t*)(lp), 16, 0, 0)

// ---------------------------------------------------------------------------
// k_bounds: row_start[s] = first row r with index[r] >= s  (index sorted).
// ---------------------------------------------------------------------------
__global__ void k_bounds(const int* __restrict__ idx,
                         int* __restrict__ row_start, int N) {
  int r = blockIdx.x * blockDim.x + threadIdx.x;
  if (r >= N) return;
  int cur  = min(max(idx[r], 0), SEGS - 1);
  int prev = (r == 0) ? -1 : min(max(idx[r - 1], 0), SEGS - 1);
  for (int s = prev + 1; s <= cur; ++s) row_start[s] = r;
  if (r == N - 1) {
    for (int s = cur + 1; s <= SEGS; ++s) row_start[s] = N;
  }
}

// ---------------------------------------------------------------------------
// k_pack: W[K][128] f32 -> f16 fragments for mfma_f32_16x16x32_f16.
// Lane l, elem e of frag f = cb*T + t (T=K/32):  k = t*32+(l>>4)*8+e,
// c = cb*16+(l&15).  Serve as B-frags of W and A-frags of W^T.
// ---------------------------------------------------------------------------
__global__ void k_pack(const float* __restrict__ W, f16* __restrict__ out, int K) {
  const int T = K >> 5;
  int i = blockIdx.x * blockDim.x + threadIdx.x;
  if (i >= K * DH) return;
  int e = i & 7, l = (i >> 3) & 63, f = i >> 9;
  int t = f % T, cb = f / T;
  int k = t * 32 + ((l >> 4) << 3) + e;
  int c = cb * 16 + (l & 15);
  out[i] = (f16)W[k * DH + c];
}

__device__ __forceinline__ f16x8 ldfrag(const f16* __restrict__ p, int f, int lane) {
  return *(const f16x8*)(p + (((size_t)f * 64 + lane) << 3));
}

__device__ __forceinline__ f16x8 cvt8(f32x4 u0, f32x4 u1) {
  f16x8 r;
  r[0] = (f16)u0[0]; r[1] = (f16)u0[1]; r[2] = (f16)u0[2]; r[3] = (f16)u0[3];
  r[4] = (f16)u1[0]; r[5] = (f16)u1[1]; r[6] = (f16)u1[2]; r[7] = (f16)u1[3];
  return r;
}

// ---------------------------------------------------------------------------
// k_fused: block owns segments [s0, s0+64), rows [row_start[s0], row_start[s0+64)).
// x is prefetched one 64-row tile ahead via global_load_lds with a source-side
// XOR swizzle (chunk ^= row&7) so frag-layout ds_read_b128 is ~conflict-free.
// ---------------------------------------------------------------------------
__global__ __launch_bounds__(256, 2) void k_fused(
    const float* __restrict__ x, const int* __restrict__ idx,
    const int* __restrict__ row_start,
    const f16* __restrict__ vWp, const f16* __restrict__ vPp,
    const f16* __restrict__ aW0p, const f16* __restrict__ aP0p,
    const f16* __restrict__ aW1p, const f16* __restrict__ voWp,
    const float* __restrict__ vb,  const float* __restrict__ vob,
    const float* __restrict__ vlW, const float* __restrict__ vlb,
    const float* __restrict__ ab0, const float* __restrict__ ab1,
    const float* __restrict__ alW, const float* __restrict__ alb,
    float* __restrict__ out)
{
  __shared__ __align__(16) f16   Hsh[8 * 512];     //  8 KB  h relayout (per-cf pass)
  __shared__ __align__(16) f16   Ash[16 * 512];    // 16 KB  a1 A-frags / stage-2 agg
  __shared__ __align__(16) float xb[2][4096];      // 32 KB  x tile double-buffer
  __shared__ __align__(16) int   segsh[2][64];
  __shared__ __align__(16) float advp[4][64];
  __shared__ float advsum_sh[SPB];
  __shared__ float corr_sh[SPB];

  const int tid  = threadIdx.x;
  const int wave = tid >> 6, lane = tid & 63;
  const int lg = lane >> 4, lm = lane & 15;
  const int s0 = blockIdx.x * SPB;
  const int send = min(s0 + SPB, SEGS);
  const int rbeg = row_start[s0], rend = row_start[send];

  // transposed-layout scalars (ch = wave*32 + i*16 + lg*4 + q)
  float b0r[2][4], b1r[2][4], alwr[2][4];
#pragma unroll
  for (int i = 0; i < 2; ++i)
#pragma unroll
    for (int q = 0; q < 4; ++q) {
      const int ch = wave * 32 + i * 16 + lg * 4 + q;
      b0r[i][q] = ab0[ch]; b1r[i][q] = ab1[ch]; alwr[i][q] = alW[ch];
    }
  // C-layout scalars (ch = wave*32 + cf*16 + lm)
  const int cc0 = wave * 32 + lm, cc1 = cc0 + 16;
  const float vbr[2]  = {vb[cc0],  vb[cc1]};
  const float vobr[2] = {vob[cc0], vob[cc1]};
  const float vlwr[2] = {vlW[cc0], vlW[cc1]};
  const float alb0 = alb[0], vlb0 = vlb[0];

  // persistent K=64 weight fragments (64 VGPR)
  f16x8 bW[2][2], bP[2][2], w0t[2][2], p0t[2][2];
#pragma unroll
  for (int cf = 0; cf < 2; ++cf)
#pragma unroll
    for (int t = 0; t < 2; ++t) {
      bW [cf][t] = ldfrag(vWp,  (wave * 2 + cf) * 2 + t, lane);
      bP [cf][t] = ldfrag(vPp,  (wave * 2 + cf) * 2 + t, lane);
      w0t[cf][t] = ldfrag(aW0p, (wave * 2 + cf) * 2 + t, lane);
      p0t[cf][t] = ldfrag(aP0p, (wave * 2 + cf) * 2 + t, lane);
    }

  f32x4 agg_c[4][2];
#pragma unroll
  for (int rf = 0; rf < 4; ++rf)
#pragma unroll
    for (int cf = 0; cf < 2; ++cf) { f32x4 z = {0.f,0.f,0.f,0.f}; agg_c[rf][cf] = z; }

  if (tid < SPB) advsum_sh[tid] = 0.f;

  // ---- prologue: prefetch tile 0 (x + segsh) ----
  if (rbeg < rend) {
#pragma unroll
    for (int i = 0; i < 4; ++i) {
      const int p = ((wave * 4 + i) << 10) + lane * 16;   // linear LDS byte slot
      const int prow = p >> 8;                            // row within tile
      const int cl = (p >> 4) & 15;                       // 16B chunk (LDS view)
      const int ch = (cl & 8) | ((cl ^ prow) & 7);        // source chunk (swizzled)
      const float* src = x + (size_t)min(rbeg + prow, NROWS - 1) * DIN + ch * 4;
      GLOAD_LDS16(src, &xb[0][(wave * 4 + i) * 256]);
    }
  }
  if (tid < 64) {
    const int n0 = min(64, rend - rbeg);
    int sr = idx[min(rbeg + tid, NROWS - 1)];
    segsh[0][tid] = (tid < n0) ? sr - s0 : -1;
  }
  __syncthreads();   // drains prologue prefetch (vmcnt 0) + segsh

  int par = 0;
  for (int rt = rbeg; rt < rend; rt += 64, par ^= 1) {
    const int nrows = min(64, rend - rt);
    const bool has_next = (rt + 64) < rend;
    const int nrows_next = has_next ? min(64, rend - rt - 64) : 0;

    // (a) aW1 frags: issue FIRST (oldest) so GEMM2's wait leaves the
    //     younger x-prefetch in flight
    f16x8 w1[2][4];
#pragma unroll
    for (int rfc = 0; rfc < 2; ++rfc)
#pragma unroll
      for (int t = 0; t < 4; ++t)
        w1[rfc][t] = ldfrag(aW1p, (wave * 2 + rfc) * 4 + t, lane);

    // (b) idx prefetch (register; consumed post-GEMM2)
    const int seg_raw = idx[min(rt + 64 + tid, NROWS - 1)];

    // (c) async x prefetch for next tile -> xb[par^1] (survives raw B1)
    if (has_next) {
#pragma unroll
      for (int i = 0; i < 4; ++i) {
        const int p = ((wave * 4 + i) << 10) + lane * 16;
        const int prow = p >> 8;
        const int cl = (p >> 4) & 15;
        const int ch = (cl & 8) | ((cl ^ prow) & 7);
        const float* src = x + (size_t)min(rt + 64 + prow, NROWS - 1) * DIN + ch * 4;
        GLOAD_LDS16(src, &xb[par ^ 1][(wave * 4 + i) * 256]);
      }
    }

    // (d) current x tile: LDS -> A/B^T fragments (inverse swizzle on read)
    f16x8 ax[4][2];
#pragma unroll
    for (int rf = 0; rf < 4; ++rf) {
      const int row = rf * 16 + lm;
      const bool ok = row < nrows;
      const int rb = row * 64;
      const int swb = (lg * 2) ^ (row & 7);
#pragma unroll
      for (int t = 0; t < 2; ++t) {
        f32x4 u0 = *(const f32x4*)&xb[par][rb + t * 32 + swb * 4];
        f32x4 u1 = *(const f32x4*)&xb[par][rb + t * 32 + (swb ^ 1) * 4];
        f32x4 zz = {0.f, 0.f, 0.f, 0.f};
        if (!ok) { u0 = zz; u1 = zz; }
        ax[rf][t] = cvt8(u0, u1);
      }
    }

    // ---- phase V: h = relu(x@vW+vb)+x@vP -> hb B-frags via per-cf Hsh pass ----
    f16x8 hb[2][2];
    {
      f32x4 cA[4][2], cB[4][2];
#pragma unroll
      for (int rf = 0; rf < 4; ++rf)
#pragma unroll
        for (int cf = 0; cf < 2; ++cf) { f32x4 z = {0.f,0.f,0.f,0.f}; cA[rf][cf] = z; cB[rf][cf] = z; }
#pragma unroll
      for (int t = 0; t < 2; ++t)
#pragma unroll
        for (int rf = 0; rf < 4; ++rf)
#pragma unroll
          for (int cf = 0; cf < 2; ++cf) {
            cA[rf][cf] = MFMA16(ax[rf][t], bW[cf][t], cA[rf][cf]);
            cB[rf][cf] = MFMA16(ax[rf][t], bP[cf][t], cB[rf][cf]);
          }
#pragma unroll
      for (int cf = 0; cf < 2; ++cf) {
#pragma unroll
        for (int rf = 0; rf < 4; ++rf) {
          f16x4v hv;
#pragma unroll
          for (int q = 0; q < 4; ++q)
            hv[q] = (f16)(fmaxf(cA[rf][cf][q] + vbr[cf], 0.f) + cB[rf][cf][q]);
          const int laneb = ((rf & 1) * 2 + (lg >> 1)) * 16 + lm;
          const int off = ((wave * 2 + (rf >> 1)) * 64 + laneb) * 8 + (lg & 1) * 4;
          *(f16x4v*)&Hsh[off] = hv;
        }
#pragma unroll
        for (int t = 0; t < 2; ++t)   // wave-private read-back (lgkm-ordered)
          hb[cf][t] = *(const f16x8*)&Hsh[((wave * 2 + t) * 64 + lane) * 8];
      }
    }

    // ---- phase A' (transposed): a1^T = relu(W0^T@x^T+b0)+P0^T@x^T ----
    float pA[4] = {0.f, 0.f, 0.f, 0.f};
    {
      f32x4 cA2[2][4], cB2[2][4];
#pragma unroll
      for (int rfc = 0; rfc < 2; ++rfc)
#pragma unroll
        for (int cfr = 0; cfr < 4; ++cfr) { f32x4 z = {0.f,0.f,0.f,0.f}; cA2[rfc][cfr] = z; cB2[rfc][cfr] = z; }
#pragma unroll
      for (int t = 0; t < 2; ++t)
#pragma unroll
        for (int rfc = 0; rfc < 2; ++rfc)
#pragma unroll
          for (int cfr = 0; cfr < 4; ++cfr) {
            cA2[rfc][cfr] = MFMA16(w0t[rfc][t], ax[cfr][t], cA2[rfc][cfr]);
            cB2[rfc][cfr] = MFMA16(p0t[rfc][t], ax[cfr][t], cB2[rfc][cfr]);
          }
#pragma unroll
      for (int rfc = 0; rfc < 2; ++rfc)
#pragma unroll
        for (int cfr = 0; cfr < 4; ++cfr) {
          f16x4v av;
#pragma unroll
          for (int q = 0; q < 4; ++q) {
            float a1 = fmaxf(cA2[rfc][cfr][q] + b0r[rfc][q], 0.f) + cB2[rfc][cfr][q];
            pA[cfr] += a1 * alwr[rfc][q];
            av[q] = (f16)a1;
          }
          const int lane_a = lm + 16 * (rfc * 2 + (lg >> 1));
          const int off = ((cfr * 4 + wave) * 64 + lane_a) * 8 + (lg & 1) * 4;
          *(f16x4v*)&Ash[off] = av;
        }
    }

    // ---- agg += I @ H  (one-hot indicator, register-built) ----
    {
#pragma unroll
      for (int t = 0; t < 2; ++t) {
        const i32x4 sa = *(const i32x4*)&segsh[par][t * 32 + lg * 8];
        const i32x4 sb = *(const i32x4*)&segsh[par][t * 32 + lg * 8 + 4];
#pragma unroll
        for (int rf = 0; rf < 4; ++rf) {
          const int tgt = rf * 16 + lm;
          f16x8 ind;
#pragma unroll
          for (int e = 0; e < 4; ++e) {
            ind[e]     = (sa[e] == tgt) ? (f16)1.f : (f16)0.f;
            ind[e + 4] = (sb[e] == tgt) ? (f16)1.f : (f16)0.f;
          }
#pragma unroll
          for (int cf = 0; cf < 2; ++cf)
            agg_c[rf][cf] = MFMA16(ind, hb[cf][t], agg_c[rf][cf]);
        }
      }
    }

    // B1: LDS-only ordering — raw barrier, lgkmcnt only (prefetch stays in flight)
    asm volatile("s_waitcnt lgkmcnt(0)" ::: "memory");
    __builtin_amdgcn_s_barrier();

    // ---- GEMM2^T: relu(W1^T@a1^T+b1)·alW (+pA) -> per-row adv partials ----
    {
      f32x4 c2[2][4];
#pragma unroll
      for (int rfc = 0; rfc < 2; ++rfc)
#pragma unroll
        for (int cfr = 0; cfr < 4; ++cfr) { f32x4 z = {0.f,0.f,0.f,0.f}; c2[rfc][cfr] = z; }
#pragma unroll
      for (int t = 0; t < 4; ++t)
#pragma unroll
        for (int cfr = 0; cfr < 4; ++cfr) {
          const f16x8 bv = *(const f16x8*)&Ash[((cfr * 4 + t) * 64 + lane) * 8];
#pragma unroll
          for (int rfc = 0; rfc < 2; ++rfc)
            c2[rfc][cfr] = MFMA16(w1[rfc][t], bv, c2[rfc][cfr]);
        }
#pragma unroll
      for (int cfr = 0; cfr < 4; ++cfr) {
        float s = pA[cfr];
#pragma unroll
        for (int rfc = 0; rfc < 2; ++rfc)
#pragma unroll
          for (int q = 0; q < 4; ++q)
            s += fmaxf(c2[rfc][cfr][q] + b1r[rfc][q], 0.f) * alwr[rfc][q];
        s += __shfl_xor(s, 16);
        s += __shfl_xor(s, 32);
        if (lg == 0) advp[wave][cfr * 16 + lm] = s;
      }
    }

    // segsh for next tile (idx load from (b) completes here)
    if (tid < 64) segsh[par ^ 1][tid] = (tid < nrows_next) ? seg_raw - s0 : -1;

    __syncthreads();   // B2: drains x prefetch + advp + segsh

    if (wave == 2) {   // finalize: adv out + segmented suffix scan -> advsum
      const int r = lane;
      const bool valid = r < nrows;
      const int sg = valid ? segsh[par][r] : -1;
      float acc = 0.f;
      if (valid) {
        float adv = advp[0][r] + advp[1][r] + advp[2][r] + advp[3][r] + alb0;
        out[rt + r] = adv;
        acc = adv;
      }
#pragma unroll
      for (int d = 1; d < 64; d <<= 1) {
        float nv = __shfl_down(acc, d);
        int   ns = __shfl_down(sg, d);
        if (r + d < 64 && ns == sg) acc += nv;
      }
      if (valid && (r == 0 || segsh[par][r - 1] != sg)) advsum_sh[sg] += acc;
    }
  }  // tile loop

  // ---------------- stage 2: segment res_block + value head ----------------
  __syncthreads();
#pragma unroll
  for (int rf = 0; rf < 4; ++rf)
#pragma unroll
    for (int cf = 0; cf < 2; ++cf) {
      const int hi = 16 * (cf * 2 + (lm >> 3));
#pragma unroll
      for (int q = 0; q < 4; ++q)
        Ash[((rf * 4 + wave) * 64 + (lg * 4 + q) + hi) * 8 + (lm & 7)] = (f16)agg_c[rf][cf][q];
    }
  __syncthreads();

  {
    f16x8 bvo[2][4];
#pragma unroll
    for (int cf = 0; cf < 2; ++cf)
#pragma unroll
      for (int t = 0; t < 4; ++t)
        bvo[cf][t] = ldfrag(voWp, (wave * 2 + cf) * 4 + t, lane);
    f32x4 c3[4][2];
#pragma unroll
    for (int rf = 0; rf < 4; ++rf)
#pragma unroll
      for (int cf = 0; cf < 2; ++cf) { f32x4 z = {0.f,0.f,0.f,0.f}; c3[rf][cf] = z; }
#pragma unroll
    for (int rf = 0; rf < 4; ++rf)
#pragma unroll
      for (int t = 0; t < 4; ++t) {
        const f16x8 av = *(const f16x8*)&Ash[((rf * 4 + t) * 64 + lane) * 8];
#pragma unroll
        for (int cf = 0; cf < 2; ++cf)
          c3[rf][cf] = MFMA16(av, bvo[cf][t], c3[rf][cf]);
      }
    f32x4 p3[4];
#pragma unroll
    for (int rf = 0; rf < 4; ++rf)
#pragma unroll
      for (int q = 0; q < 4; ++q) {
        float s = 0.f;
#pragma unroll
        for (int cf = 0; cf < 2; ++cf) {
          float h2 = fmaxf(c3[rf][cf][q] + vobr[cf], 0.f) + agg_c[rf][cf][q];
          s += h2 * vlwr[cf];
        }
        p3[rf][q] = s;
      }
#pragma unroll
    for (int m = 1; m <= 8; m <<= 1)
#pragma unroll
      for (int rf = 0; rf < 4; ++rf)
#pragma unroll
        for (int q = 0; q < 4; ++q)
          p3[rf][q] += __shfl_xor(p3[rf][q], m);
    if (lm == 0) {
#pragma unroll
      for (int rf = 0; rf < 4; ++rf)
        *(f32x4*)&advp[wave][rf * 16 + lg * 4] = p3[rf];
    }
  }
  __syncthreads();

  if (tid < send - s0) {
    float sv = advp[0][tid] + advp[1][tid] + advp[2][tid] + advp[3][tid] + vlb0;
    int cnt = row_start[s0 + tid + 1] - row_start[s0 + tid];
    corr_sh[tid] = sv - advsum_sh[tid] / (float)max(cnt, 1);
  }
  __syncthreads();

  for (int r = rbeg + tid; r < rend; r += 256) {
    const int s = idx[r];
    out[r] += corr_sh[s - s0];
    out[NROWS + r] = (float)s;
  }
}

extern "C" void kernel_launch(void* const* d_in, const int* in_sizes, int n_in,
                              void* d_out, int out_size, void* d_ws, size_t ws_size,
                              hipStream_t stream) {
  (void)n_in; (void)out_size; (void)ws_size;
  const float* x   = (const float*)d_in[0];
  const int*   idx = (const int*)d_in[1];
  const float* vW  = (const float*)d_in[2];
  const float* vb  = (const float*)d_in[3];
  const float* vP  = (const float*)d_in[4];
  const float* voW = (const float*)d_in[5];
  const float* vob = (const float*)d_in[6];
  const float* vlW = (const float*)d_in[7];
  const float* vlb = (const float*)d_in[8];
  const float* aW0 = (const float*)d_in[9];
  const float* ab0 = (const float*)d_in[10];
  const float* aP0 = (const float*)d_in[11];
  const float* aW1 = (const float*)d_in[12];
  const float* ab1 = (const float*)d_in[13];
  const float* alW = (const float*)d_in[14];
  const float* alb = (const float*)d_in[15];

  const int N = in_sizes[0] / DIN;
  float* out = (float*)d_out;

  int* row_start = (int*)d_ws;                                  // SEGS+1 ints
  char* pkbase = (char*)d_ws + (((SEGS + 1) * 4 + 127) & ~127);
  f16* vWp  = (f16*)pkbase;
  f16* vPp  = vWp  + 8192;
  f16* aW0p = vPp  + 8192;
  f16* aP0p = aW0p + 8192;
  f16* aW1p = aP0p + 8192;
  f16* voWp = aW1p + 16384;

  k_bounds<<<(N + 255) / 256, 256, 0, stream>>>(idx, row_start, N);
  k_pack<<<32, 256, 0, stream>>>(vW,  vWp,  64);
  k_pack<<<32, 256, 0, stream>>>(vP,  vPp,  64);
  k_pack<<<32, 256, 0, stream>>>(aW0, aW0p, 64);
  k_pack<<<32, 256, 0, stream>>>(aP0, aP0p, 64);
  k_pack<<<64, 256, 0, stream>>>(aW1, aW1p, 128);
  k_pack<<<64, 256, 0, stream>>>(voW, voWp, 128);

  const int nblk = (SEGS + SPB - 1) / SPB;
  k_fused<<<nblk, 256, 0, stream>>>(x, idx, row_start,
                                    vWp, vPp, aW0p, aP0p, aW1p, voWp,
                                    vb, vob, vlW, vlb, ab0, ab1, alW, alb,
                                    out);
}